// Round 7
// baseline (254.403 us; speedup 1.0000x reference)
//
#include <hip/hip_runtime.h>

#define N_ROWS 128
#define IN_DIM 1024
#define OUT_DIM 1024

// out[n,o] = max_k(w[o,k] + x[n,k]) + bias[o]   (tropical matmul)
//
// R7 = R5's K-split (the only shape with 64 MB w-traffic AND 16 waves/CU)
// with R5's three defects fixed:
//  (1) butterfly 524k -> 131k shfl: waves 1-3 dump raw acc to LDS
//      (transposed [i][ks][lane] layout = lane-consecutive, conflict-free);
//      wave 0 max-combines and does the only butterfly+store.
//  (2) scratch reuses the x-tile LDS (24 KB < 32 KB) -> 4 blocks/CU kept.
//  (3) w 2-deep dbuf + fully unrolled 4-step quarter-K loop.
// Evidence driving this: per-launch marginal k is 13.13 (R3-kernel) and
// 13.15 (R6-kernel) -> identical because R6's wn-waves redundantly load
// the same w rows (actual 256 MB, not 64): 256 MB / 13.1 us = 19.6 TB/s
// = sustained L2 rate. R7 genuinely cuts w traffic to 64 MB.
// Structure: grid 16(bn) x 64(bo) = 1024 blocks = 4/CU = 16 waves/CU.
// Block: 4 waves = 4 K-quarters over the same 8n x 16o tile.
// Per wave: jn=8 rows, 16 o (og*4+r), K in [wid*256, wid*256+256).
// INSTRUMENT: 8 idempotent launches. Pre-committed: marginal <=9 us =>
// w-BW theory right (continue); ~13.1 => fixed launch overhead floor =>
// revert to single launch + declare.

__global__ __launch_bounds__(256, 4)
void tropical_linear_kernel(const float* __restrict__ x,
                            const float* __restrict__ w,
                            const float* __restrict__ bias,
                            float* __restrict__ out) {
    __shared__ float4 xs[8 * 256];   // 32 KB x-tile; reused as combine scratch

    const int tid  = threadIdx.x;
    const int wid  = tid >> 6;       // wave 0..3 = K-quarter
    const int lane = tid & 63;
    const int g    = lane & 15;      // k phase 0..15 within a step
    const int og   = lane >> 4;      // o group 0..3

    const int bn = blockIdx.x >> 6;  // 16 n-blocks
    const int bo = blockIdx.x & 63;  // 64 o-blocks (idx%8==bo%8 -> same XCD)
    const int n0 = bn * 8;
    const int obase = bo * 16 + og * 4;

    const float4* __restrict__ x4 = (const float4*)x;

    // ---- stage x tile: 2048 float4, 8 per thread, coalesced ----
#pragma unroll
    for (int i = 0; i < 8; ++i) {
        const int idx = tid + i * 256;
        xs[idx] = x4[(size_t)(n0 + (idx >> 8)) * 256 + (idx & 255)];
    }

    // w row pointers: f4 index (obase+r)*256 + wid*64 + g; steps s=0..3
    // fold into imm offsets s*16 f4 (256 B each).
    const float4* __restrict__ wp0 = (const float4*)w + (size_t)(obase + 0) * 256 + wid * 64 + g;
    const float4* __restrict__ wp1 = (const float4*)w + (size_t)(obase + 1) * 256 + wid * 64 + g;
    const float4* __restrict__ wp2 = (const float4*)w + (size_t)(obase + 2) * 256 + wid * 64 + g;
    const float4* __restrict__ wp3 = (const float4*)w + (size_t)(obase + 3) * 256 + wid * 64 + g;

    // w prologue (s=0,1) issued before the barrier: independent of LDS
    float4 wA[4], wB[4];
    wA[0] = wp0[0];  wA[1] = wp1[0];  wA[2] = wp2[0];  wA[3] = wp3[0];
    wB[0] = wp0[16]; wB[1] = wp1[16]; wB[2] = wp2[16]; wB[3] = wp3[16];

    float acc[8][4];
#pragma unroll
    for (int j = 0; j < 8; ++j)
#pragma unroll
        for (int r = 0; r < 4; ++r) acc[j][r] = -3.4e38f;

    __syncthreads();

    // per-wave LDS base: f4 col = wid*64 + s*16 + g (imm: j*256 + s*16)
    const float4* __restrict__ xsg = xs + wid * 64 + g;

    float4 xq[8];

#define TROPIC_STEP(WBUF)                                         \
    _Pragma("unroll")                                             \
    for (int j = 0; j < 8; ++j) {                                 \
        const float4 xv = xq[j];                                  \
        _Pragma("unroll")                                         \
        for (int r = 0; r < 4; ++r) {                             \
            const float s0 = WBUF[r].x + xv.x;                    \
            const float s1 = WBUF[r].y + xv.y;                    \
            const float s2 = WBUF[r].z + xv.z;                    \
            const float s3 = WBUF[r].w + xv.w;                    \
            const float m = fmaxf(fmaxf(s0, s1), s2);             \
            acc[j][r] = fmaxf(fmaxf(m, s3), acc[j][r]);           \
        }                                                         \
    }

    // ---- 4 k-steps (this wave's K-quarter), w double-buffered ----
#pragma unroll
    for (int j = 0; j < 8; ++j) xq[j] = xsg[j * 256];            // s=0
    TROPIC_STEP(wA)
    wA[0] = wp0[32]; wA[1] = wp1[32]; wA[2] = wp2[32]; wA[3] = wp3[32];

#pragma unroll
    for (int j = 0; j < 8; ++j) xq[j] = xsg[j * 256 + 16];       // s=1
    TROPIC_STEP(wB)
    wB[0] = wp0[48]; wB[1] = wp1[48]; wB[2] = wp2[48]; wB[3] = wp3[48];

#pragma unroll
    for (int j = 0; j < 8; ++j) xq[j] = xsg[j * 256 + 32];       // s=2
    TROPIC_STEP(wA)

#pragma unroll
    for (int j = 0; j < 8; ++j) xq[j] = xsg[j * 256 + 48];       // s=3
    TROPIC_STEP(wB)

#undef TROPIC_STEP

    // ---- combine K-quarter partials via LDS (reuse xs), then ONE
    //      butterfly on wave 0 only ----
    __syncthreads();                 // everyone done reading xs
    if (wid != 0) {
        // transposed layout [i][wid-1][lane]: lane-consecutive f4 writes,
        // conflict-free (a [lane][8] pitch-128B layout would be 32-way).
#pragma unroll
        for (int i = 0; i < 8; ++i) {
            xs[(i * 3 + (wid - 1)) * 64 + lane] =
                make_float4(acc[i][0], acc[i][1], acc[i][2], acc[i][3]);
        }
    }
    __syncthreads();

    if (wid == 0) {
#pragma unroll
        for (int i = 0; i < 8; ++i) {
#pragma unroll
            for (int s = 0; s < 3; ++s) {
                const float4 p = xs[(i * 3 + s) * 64 + lane];
                acc[i][0] = fmaxf(acc[i][0], p.x);
                acc[i][1] = fmaxf(acc[i][1], p.y);
                acc[i][2] = fmaxf(acc[i][2], p.z);
                acc[i][3] = fmaxf(acc[i][3], p.w);
            }
        }

        // reduce across the 16 k-phases (lane bits 0..3)
#pragma unroll
        for (int j = 0; j < 8; ++j) {
#pragma unroll
            for (int r = 0; r < 4; ++r) {
                float v = acc[j][r];
                v = fmaxf(v, __shfl_xor(v, 1, 64));
                v = fmaxf(v, __shfl_xor(v, 2, 64));
                v = fmaxf(v, __shfl_xor(v, 4, 64));
                v = fmaxf(v, __shfl_xor(v, 8, 64));
                acc[j][r] = v;
            }
        }

        // all 16 g-lanes per og now identical; lane g stores one float2:
        // j = g>>1, column pair pr = g&1 (static acc index, rule #20)
        const int jj = g >> 1;
        const int pr = g & 1;
        float2 res = make_float2(0.f, 0.f);
#pragma unroll
        for (int j = 0; j < 8; ++j) {
            if (jj == j) {
                res.x = pr ? acc[j][2] : acc[j][0];
                res.y = pr ? acc[j][3] : acc[j][1];
            }
        }
        const int oc = obase + pr * 2;
        const float2 bv = *(const float2*)&bias[oc];
        res.x += bv.x;
        res.y += bv.y;
        *(float2*)&out[(size_t)(n0 + jj) * OUT_DIM + oc] = res;
    }
}

extern "C" void kernel_launch(void* const* d_in, const int* in_sizes, int n_in,
                              void* d_out, int out_size, void* d_ws, size_t ws_size,
                              hipStream_t stream) {
    const float* x    = (const float*)d_in[0];   // [128,1024]
    const float* w    = (const float*)d_in[1];   // [1024,1024]
    const float* bias = (const float*)d_in[2];   // [1024]
    float* out = (float*)d_out;                  // [128,1024]

    dim3 grid(1024);
    dim3 block(256);
    // 8 idempotent launches: marginal per launch = warm kernel + gap.
    // Instrument round — reverts to single launch next round.
    for (int rep = 0; rep < 8; ++rep) {
        hipLaunchKernelGGL(tropical_linear_kernel, grid, block, 0, stream,
                           x, w, bias, out);
    }
}

// Round 8
// 82.550 us; speedup vs baseline: 3.0818x; 3.0818x over previous
//
#include <hip/hip_runtime.h>

#define N_ROWS 128
#define IN_DIM 1024
#define OUT_DIM 1024

// out[n,o] = max_k(w[o,k] + x[n,k]) + bias[o]   (tropical matmul)
//
// R8: GAP-vs-KERNEL split probe.
// Evidence so far: per-launch marginal = 13.13 us (R4: 1024x256 blocks)
// vs 13.15 us (R6: 256x1024 blocks) — identical to 0.15% across
// radically different kernels; K-split variants (R5/R7) = 24.5-27.6 us
// (R5's profiled VGPR_Count=56 < the >=96 its arrays need -> spill).
// No kernel-resource model yields a structure-invariant 13 us (VALU
// floor 2.6, LDS floor 2.6, HBM floor 0.8). Theory: per-launch graph
// dispatch gap ~10-11 us dominates; kernel is ~2-3 us.
// Probe: 1 real launch (proven R3 kernel) + 7 EMPTY launches (grid 1,
// block 64, no memory access). Marginal of empty = gap + epsilon.
//   Pre-committed: dur ~150 => gap-dominated -> revert to single launch
//   and declare harness floor.  dur ~86 => kernel is real 13 us ->
//   continue optimizing with rocprof on the kernel.

__global__ __launch_bounds__(256, 4)
void tropical_linear_kernel(const float* __restrict__ x,
                            const float* __restrict__ w,
                            const float* __restrict__ bias,
                            float* __restrict__ out) {
    __shared__ float4 xs[2 * 256];   // 8 KB

    const int tid  = threadIdx.x;
    const int wid  = tid >> 6;       // wave 0..3
    const int lane = tid & 63;
    const int g    = lane & 15;      // k phase 0..15
    const int og   = lane >> 4;      // o group 0..3

    const int bn = blockIdx.x >> 4;  // 64 n-blocks
    const int bo = blockIdx.x & 15;  // 16 o-blocks (idx%8==bo%8 -> same XCD)
    const int n0 = bn * 2;
    const int obase = bo * 64 + wid * 16 + og * 4;

    const float4* __restrict__ x4 = (const float4*)x;

    // ---- stage x tile: 512 float4, 2 per thread, coalesced ----
#pragma unroll
    for (int i = 0; i < 2; ++i) {
        const int idx = tid + i * 256;
        xs[idx] = x4[(size_t)(n0 + (idx >> 8)) * 256 + (idx & 255)];
    }

    // w row pointers (row stride 4096 B > 13-bit imm, so 4 bases; the
    // 16 k-steps per row fold into imm offsets t*256 <= 3840).
    const float4* __restrict__ wp0 = (const float4*)w + (size_t)(obase + 0) * 256 + g;
    const float4* __restrict__ wp1 = (const float4*)w + (size_t)(obase + 1) * 256 + g;
    const float4* __restrict__ wp2 = (const float4*)w + (size_t)(obase + 2) * 256 + g;
    const float4* __restrict__ wp3 = (const float4*)w + (size_t)(obase + 3) * 256 + g;

    // w prologue loads (t=0,1) issued before the barrier: independent of LDS
    float4 wA[4], wB[4];
    wA[0] = wp0[0];  wA[1] = wp1[0];  wA[2] = wp2[0];  wA[3] = wp3[0];
    wB[0] = wp0[16]; wB[1] = wp1[16]; wB[2] = wp2[16]; wB[3] = wp3[16];

    float acc[2][4];
#pragma unroll
    for (int j = 0; j < 2; ++j)
#pragma unroll
        for (int r = 0; r < 4; ++r) acc[j][r] = -3.4e38f;

    __syncthreads();

    const float4* __restrict__ xsg = xs + g;

    float4 xA[2], xB[2];
#pragma unroll
    for (int j = 0; j < 2; ++j) xA[j] = xsg[j * 256];    // t=0

#define TROPIC_STEP(WBUF, XBUF)                                   \
    _Pragma("unroll")                                             \
    for (int j = 0; j < 2; ++j) {                                 \
        const float4 xv = XBUF[j];                                \
        _Pragma("unroll")                                         \
        for (int r = 0; r < 4; ++r) {                             \
            const float s0 = WBUF[r].x + xv.x;                    \
            const float s1 = WBUF[r].y + xv.y;                    \
            const float s2 = WBUF[r].z + xv.z;                    \
            const float s3 = WBUF[r].w + xv.w;                    \
            const float m = fmaxf(fmaxf(s0, s1), s2);             \
            acc[j][r] = fmaxf(fmaxf(m, s3), acc[j][r]);           \
        }                                                         \
    }

    // Steady state: 7 iterations x 2 k-steps; tail handles t=14,15.
#pragma unroll 1
    for (int tt = 0; tt < 7; ++tt) {
        const int t0 = 2 * tt;
#pragma unroll
        for (int j = 0; j < 2; ++j) xB[j] = xsg[j * 256 + (t0 + 1) * 16];
        TROPIC_STEP(wA, xA)
        wA[0] = wp0[(t0 + 2) * 16]; wA[1] = wp1[(t0 + 2) * 16];
        wA[2] = wp2[(t0 + 2) * 16]; wA[3] = wp3[(t0 + 2) * 16];
#pragma unroll
        for (int j = 0; j < 2; ++j) xA[j] = xsg[j * 256 + (t0 + 2) * 16];
        TROPIC_STEP(wB, xB)
        wB[0] = wp0[(t0 + 3) * 16]; wB[1] = wp1[(t0 + 3) * 16];
        wB[2] = wp2[(t0 + 3) * 16]; wB[3] = wp3[(t0 + 3) * 16];
    }
#pragma unroll
    for (int j = 0; j < 2; ++j) xB[j] = xsg[j * 256 + 15 * 16];
    TROPIC_STEP(wA, xA)
    TROPIC_STEP(wB, xB)

#undef TROPIC_STEP

    // ---- reduce across the 16 k-phases (lane bits 0..3) ----
#pragma unroll
    for (int j = 0; j < 2; ++j) {
#pragma unroll
        for (int r = 0; r < 4; ++r) {
            float v = acc[j][r];
            v = fmaxf(v, __shfl_xor(v, 1, 64));
            v = fmaxf(v, __shfl_xor(v, 2, 64));
            v = fmaxf(v, __shfl_xor(v, 4, 64));
            v = fmaxf(v, __shfl_xor(v, 8, 64));
            acc[j][r] = v;
        }
    }

    if (g < 4) {
        const int jj = g & 1;        // n-row within tile
        const int pr = g >> 1;       // which float2 column pair
        float2 res = make_float2(0.f, 0.f);
#pragma unroll
        for (int j = 0; j < 2; ++j) {
            if (jj == j) {           // static indices only
                res.x = pr ? acc[j][2] : acc[j][0];
                res.y = pr ? acc[j][3] : acc[j][1];
            }
        }
        const int oc = obase + pr * 2;
        const float2 bv = *(const float2*)&bias[oc];
        res.x += bv.x;
        res.y += bv.y;
        *(float2*)&out[(size_t)(n0 + jj) * OUT_DIM + oc] = res;
    }
}

// Empty probe kernel: measures pure per-launch dispatch gap.
__global__ void nop_kernel() {}

extern "C" void kernel_launch(void* const* d_in, const int* in_sizes, int n_in,
                              void* d_out, int out_size, void* d_ws, size_t ws_size,
                              hipStream_t stream) {
    const float* x    = (const float*)d_in[0];   // [128,1024]
    const float* w    = (const float*)d_in[1];   // [1024,1024]
    const float* bias = (const float*)d_in[2];   // [1024]
    float* out = (float*)d_out;                  // [128,1024]

    dim3 grid(1024);
    dim3 block(256);
    hipLaunchKernelGGL(tropical_linear_kernel, grid, block, 0, stream,
                       x, w, bias, out);
    // 7 empty launches: marginal per launch = dispatch gap + epsilon.
    for (int rep = 0; rep < 7; ++rep) {
        hipLaunchKernelGGL(nop_kernel, dim3(1), dim3(64), 0, stream);
    }
}

// Round 9
// 66.038 us; speedup vs baseline: 3.8524x; 1.2500x over previous
//
#include <hip/hip_runtime.h>

#define N_ROWS 128
#define IN_DIM 1024
#define OUT_DIM 1024

// out[n,o] = max_k(w[o,k] + x[n,k]) + bias[o]   (tropical matmul)
//
// R9: INVERT DATA PLACEMENT — w staged in LDS once per block, x in regs.
// Evidence chain: R8 nop-probe -> launch gap = 1.54 us, so R3's 13.13 us
// marginal is ~11.6 us REAL kernel time. R3/R6 both move ~256-268 MB of
// w through VMEM/L2 (per-wave redundant reads): 268 MB / 13.1 us =
// 20 TB/s = sustained L2 rate -> w-stream-bound. Every x-in-LDS variant
// re-reads w per wave; fix = w read from global ONCE per block.
//
// Structure: block = 256 thr = 4 waves; tile 16n x 16o; grid 8 x 64
//   = 512 blocks = 2 blocks/CU = 8 waves/CU (2/SIMD, VGPR ~170).
// - w-panel (16 o-rows x 4 KB = 64 KB) -> LDS once; ONE barrier.
// - wave wid owns rows n0+wid*4..+3; lane l owns k-slice {f4 s*64+l},
//   x regs = 4 rows x 4 f4 = 64 VGPR, loads coalesced (lane-consecutive).
// - main loop (o unrolled x16): 4 ds_read_b128 + 96 VALU per o
//   -> per-CU LDS 6.1k cyc == VALU 6.1k cyc (parity); VMEM total 64 MB
//   (w 32 + x 32) vs R3's 268 MB.
// - k-reduce: per-wave LDS scratch transpose (stride 65 -> 2-way banked
//   = free), 64 b32 writes + 64 b32 reads, 4 indep fold chains; no
//   cross-wave dep (scratch reuses w-LDS AFTER the all-waves barrier).
// LDS 66560 B x 2 blocks = 133 KB <= 160. XCD: idx%8 == bo%8 -> same-bo
// blocks share an XCD; w-resident 512 KB/XCD.
// Predicted: kernel ~6 us; dur_us 71.8 -> 64-66.

__global__ __launch_bounds__(256, 2)
void tropical_linear_kernel(const float* __restrict__ x,
                            const float* __restrict__ w,
                            const float* __restrict__ bias,
                            float* __restrict__ out) {
    // w-panel view: 16 rows x 256 f4 = 64 KB; later reused as 4 per-wave
    // reduction scratchpads of 64x65 floats (16.6 KB each).
    __shared__ float lds_raw[4 * 64 * 65];          // 66560 B
    float4* wlds = (float4*)lds_raw;

    const int tid  = threadIdx.x;
    const int wid  = tid >> 6;       // wave 0..3 -> rows wid*4..+3
    const int lane = tid & 63;       // k-slice owner: f4s {s*64+lane}

    const int bn = blockIdx.x >> 6;  // 8 n-blocks
    const int bo = blockIdx.x & 63;  // 64 o-blocks (idx%8==bo%8 -> same XCD)
    const int n0 = bn * 16;
    const int o0 = bo * 16;

    // ---- stage w panel: 4096 f4, 16 per thread, coalesced ----
    const float4* __restrict__ wg = (const float4*)w + (size_t)o0 * 256;
#pragma unroll
    for (int i = 0; i < 16; ++i) {
        const int idx = tid + i * 256;
        wlds[idx] = wg[idx];
    }

    // ---- x -> registers: 4 rows x 4 f4 per lane, coalesced ----
    const float4* __restrict__ xg =
        (const float4*)x + (size_t)(n0 + wid * 4) * 256 + lane;
    float4 xr[4][4];
#pragma unroll
    for (int j = 0; j < 4; ++j)
#pragma unroll
        for (int s = 0; s < 4; ++s)
            xr[j][s] = xg[j * 256 + s * 64];

    float acc[4][16];
#pragma unroll
    for (int j = 0; j < 4; ++j)
#pragma unroll
        for (int o = 0; o < 16; ++o) acc[j][o] = -3.4e38f;

    __syncthreads();   // w-panel visible to all waves

    // ---- main loop: fully unrolled over the 16 o-rows ----
    const float4* __restrict__ wl = wlds + lane;
#pragma unroll
    for (int o = 0; o < 16; ++o) {
        float4 wv[4];
#pragma unroll
        for (int s = 0; s < 4; ++s) wv[s] = wl[o * 256 + s * 64];
#pragma unroll
        for (int j = 0; j < 4; ++j)
#pragma unroll
            for (int s = 0; s < 4; ++s) {
                const float4 xv = xr[j][s];
                const float s0 = wv[s].x + xv.x;
                const float s1 = wv[s].y + xv.y;
                const float s2 = wv[s].z + xv.z;
                const float s3 = wv[s].w + xv.w;
                const float m = fmaxf(fmaxf(s0, s1), s2);   // v_max3
                acc[j][o] = fmaxf(fmaxf(m, s3), acc[j][o]); // v_max3
            }
    }

    // ---- k-reduce across 64 lanes via per-wave LDS transpose ----
    __syncthreads();   // all waves done reading the w-panel; safe to reuse
    float* scr = lds_raw + wid * (64 * 65);

    // write: lane stores its 64 partials at scr[p*65 + lane], p=j*16+o
    // banks: (p*65+lane)%32 = (const+lane)%32 -> 2-way, free
#pragma unroll
    for (int j = 0; j < 4; ++j)
#pragma unroll
        for (int o = 0; o < 16; ++o)
            scr[(j * 16 + o) * 65 + lane] = acc[j][o];
    // same-wave LDS RAW: in-order LDS pipe + compiler lgkmcnt — no barrier

    // read: lane p folds the 64 partials of output p=(j=p>>4, o=p&15)
    // banks: (p*65+l)%32 = (p+l)%32 -> 2-way, free; 4 indep fold chains
    const float* scrp = scr + lane * 65;
    float m0 = -3.4e38f, m1 = -3.4e38f, m2 = -3.4e38f, m3 = -3.4e38f;
#pragma unroll
    for (int l = 0; l < 16; ++l) {
        m0 = fmaxf(m0, scrp[4 * l + 0]);
        m1 = fmaxf(m1, scrp[4 * l + 1]);
        m2 = fmaxf(m2, scrp[4 * l + 2]);
        m3 = fmaxf(m3, scrp[4 * l + 3]);
    }
    const float m = fmaxf(fmaxf(m0, m1), fmaxf(m2, m3));

    const int j = lane >> 4;         // row within wave
    const int o = lane & 15;         // o within panel
    out[(size_t)(n0 + wid * 4 + j) * OUT_DIM + o0 + o] = m + bias[o0 + o];
}

extern "C" void kernel_launch(void* const* d_in, const int* in_sizes, int n_in,
                              void* d_out, int out_size, void* d_ws, size_t ws_size,
                              hipStream_t stream) {
    const float* x    = (const float*)d_in[0];   // [128,1024]
    const float* w    = (const float*)d_in[1];   // [1024,1024]
    const float* bias = (const float*)d_in[2];   // [1024]
    float* out = (float*)d_out;                  // [128,1024]

    dim3 grid(512);
    dim3 block(256);
    hipLaunchKernelGGL(tropical_linear_kernel, grid, block, 0, stream,
                       x, w, bias, out);
}